// Round 13
// baseline (195.257 us; speedup 1.0000x reference)
//
#include <hip/hip_runtime.h>
#include <cstdint>

#define M_ 8192
#define N_ 4096
#define K_ 4096

typedef int   i32x4  __attribute__((ext_vector_type(4)));
typedef int   i32x16 __attribute__((ext_vector_type(16)));

__device__ __forceinline__ void async16(const void* g, void* l) {
  __builtin_amdgcn_global_load_lds(
      (const __attribute__((address_space(1))) void*)g,
      (__attribute__((address_space(3))) void*)l, 16, 0, 0);
}

// ---------------- prologue 1: x*din -> per-row i8 quant + rowsum ----------------
__global__ __launch_bounds__(256) void quant_x(const float* __restrict__ x,
                                               const float* __restrict__ din,
                                               const int* __restrict__ eidx,
                                               char* __restrict__ q,
                                               float* __restrict__ sx,
                                               float* __restrict__ qf) {
  const int row = blockIdx.x;
  const int t = threadIdx.x;
  const int e = *eidx;
  const float* xr = x + (long)row * K_;
  const float* dr = din + (long)e * K_;
  const int k0 = t * 16;
  float v[16];
#pragma unroll
  for (int j = 0; j < 4; ++j) {
    float4 xv = *(const float4*)(xr + k0 + j * 4);
    float4 dv = *(const float4*)(dr + k0 + j * 4);
    v[j*4+0] = xv.x * dv.x; v[j*4+1] = xv.y * dv.y;
    v[j*4+2] = xv.z * dv.z; v[j*4+3] = xv.w * dv.w;
  }
  float mx = 0.f;
#pragma unroll
  for (int j = 0; j < 16; ++j) mx = fmaxf(mx, fabsf(v[j]));
#pragma unroll
  for (int off = 32; off >= 1; off >>= 1) mx = fmaxf(mx, __shfl_xor(mx, off));
  __shared__ float sm[4];
  __shared__ int   ss[4];
  const int wid = t >> 6, ln = t & 63;
  if (ln == 0) sm[wid] = mx;
  __syncthreads();
  mx = fmaxf(fmaxf(sm[0], sm[1]), fmaxf(sm[2], sm[3]));
  const float scale = (mx > 0.f) ? mx * (1.f / 127.f) : 1.f;
  const float rcp   = (mx > 0.f) ? 127.f / mx : 0.f;
  int ssum = 0;
  unsigned int dw[4];
#pragma unroll
  for (int c = 0; c < 4; ++c) {
    unsigned int w = 0;
#pragma unroll
    for (int j = 0; j < 4; ++j) {
      int qi = (int)rintf(v[c*4+j] * rcp);
      ssum += qi;
      w |= ((unsigned int)(qi & 255)) << (8 * j);
    }
    dw[c] = w;
  }
  *(int4*)(q + (long)row * K_ + k0) = make_int4((int)dw[0], (int)dw[1], (int)dw[2], (int)dw[3]);
#pragma unroll
  for (int off = 32; off >= 1; off >>= 1) ssum += __shfl_xor(ssum, off);
  if (ln == 0) ss[wid] = ssum;
  __syncthreads();
  if (t == 0) {
    sx[row] = scale;
    qf[row] = (float)(ss[0] + ss[1] + ss[2] + ss[3]);
  }
}

// ---------------- prologue 2: W_int (int32, 0..126) -> i8 ----------------
__global__ __launch_bounds__(256) void repack_w(const int* __restrict__ wi,
                                                char* __restrict__ wq) {
  const long t = (long)blockIdx.x * blockDim.x + threadIdx.x;   // 1,048,576
  const long base = t * 16;
  int4 a = *(const int4*)(wi + base);
  int4 b = *(const int4*)(wi + base + 4);
  int4 c = *(const int4*)(wi + base + 8);
  int4 d = *(const int4*)(wi + base + 12);
  unsigned int w0 = (a.x & 255) | ((a.y & 255) << 8) | ((a.z & 255) << 16) | ((unsigned)(a.w & 255) << 24);
  unsigned int w1 = (b.x & 255) | ((b.y & 255) << 8) | ((b.z & 255) << 16) | ((unsigned)(b.w & 255) << 24);
  unsigned int w2 = (c.x & 255) | ((c.y & 255) << 8) | ((c.z & 255) << 16) | ((unsigned)(c.w & 255) << 24);
  unsigned int w3 = (d.x & 255) | ((d.y & 255) << 8) | ((d.z & 255) << 16) | ((unsigned)(d.w & 255) << 24);
  *(int4*)(wq + base) = make_int4((int)w0, (int)w1, (int)w2, (int)w3);
}

// ---- main GEMM: i8, 256x256 tile, BK=64B, dbuf 2x32KB, 8 waves (2Mx4N) ----
// Same structure/swizzle/sync as round 12; MFMA = 32x32x32_i8 (9.1 cyc, half
// the instructions). Wave tile 128x64 -> frags 4m x 2n of 32x32.
// A/B operand: row = lane&31, k = (lane>>5)*16+e [standard CDNA 32x32 map].
// C/D: col = lane&31, row = (reg&3)+8*(reg>>2)+4*(lane>>5) [m74/m101].
// Swizzle slot = (kh*2 + (lane>>5)) ^ (((lane&31)>>1)&3)  (both sides, r21).
#define VMC(n)   asm volatile("s_waitcnt vmcnt(" #n ")" ::: "memory")
#define BAR()    __builtin_amdgcn_s_barrier()

__global__ __launch_bounds__(512, 2) void gemm_i8(const char* __restrict__ A8,
                                                  const char* __restrict__ B8,
                                                  const float* __restrict__ zp,
                                                  const float* __restrict__ dout,
                                                  const float* __restrict__ bias,
                                                  const int* __restrict__ eidx,
                                                  const float* __restrict__ sx,
                                                  const float* __restrict__ qf,
                                                  float* __restrict__ C) {
  extern __shared__ char ldsb[];
  const int tid  = threadIdx.x;
  const int lane = tid & 63;
  const int wave = tid >> 6;
  const int wm = wave >> 2;            // 0..1 -> 128-row half
  const int wn = wave & 3;             // 0..3 -> 64-col quarter
  const int l31 = lane & 31, hi = lane >> 5;
  const int e = *eidx;

  // XCD-aware swizzle (512 % 8 == 0 -> bijective)
  const int nwg = gridDim.x;
  const int wg  = blockIdx.x;
  const int swz = (wg & 7) * (nwg >> 3) + (wg >> 3);
  const int bm = swz >> 4;
  const int bn = swz & 15;
  const long brow = (long)bm * 256;
  const long bcol = (long)bn * 256;

  // staging (identical to round 12): linear LDS dest; global src slot XOR'd
  const int gslot = (tid & 3) ^ ((tid >> 3) & 3);
  const char* pa = A8 + (brow + (tid >> 2)) * (long)K_ + gslot * 16;
  const char* pb = B8 + (bcol + (tid >> 2)) * (long)K_ + gslot * 16;

  auto STAGE = [&](int tile) {
    char* d = ldsb + (tile & 1) * 32768 + tid * 16;
    const long ko = (long)tile * 64;
    async16(pa + ko,                  d);
    async16(pa + ko + 128 * (long)K_, d + 8192);
    async16(pb + ko,                  d + 16384);
    async16(pb + ko + 128 * (long)K_, d + 24576);
  };

  // ds_read offsets: row*64 + slot*16, slot = (kh*2+hi) ^ ((l31>>1)&3)
  const int swzr = (l31 >> 1) & 3;
  const int sl0 = ((hi)     ^ swzr) * 16;   // kh = 0
  const int sl1 = ((2 + hi) ^ swzr) * 16;   // kh = 1
  int rA[4], rB[2];
#pragma unroll
  for (int m = 0; m < 4; ++m) rA[m] = (wm * 128 + m * 32 + l31) * 64;
#pragma unroll
  for (int n = 0; n < 2; ++n) rB[n] = 16384 + (wn * 64 + n * 32 + l31) * 64;

  i32x16 acc[4][2] = {};
  const int nk = K_ / 64;              // 64 K-tiles (64 bytes each)

  STAGE(0);
  for (int t = 0; t < nk; ++t) {
    if (t + 1 < nk) { STAGE(t + 1); VMC(4); }
    else            { VMC(0); }
    BAR();
    const char* bp = ldsb + (t & 1) * 32768;
    i32x4 av0[4], av1[4], bv0[2], bv1[2];
#pragma unroll
    for (int n = 0; n < 2; ++n) {
      bv0[n] = *(const i32x4*)(bp + rB[n] + sl0);
      bv1[n] = *(const i32x4*)(bp + rB[n] + sl1);
    }
#pragma unroll
    for (int m = 0; m < 4; ++m) {
      av0[m] = *(const i32x4*)(bp + rA[m] + sl0);
      av1[m] = *(const i32x4*)(bp + rA[m] + sl1);
    }
#pragma unroll
    for (int m = 0; m < 4; ++m)
#pragma unroll
      for (int n = 0; n < 2; ++n) {
        acc[m][n] = __builtin_amdgcn_mfma_i32_32x32x32_i8(av0[m], bv0[n], acc[m][n], 0, 0, 0);
        acc[m][n] = __builtin_amdgcn_mfma_i32_32x32x32_i8(av1[m], bv1[n], acc[m][n], 0, 0, 0);
      }
    BAR();
  }

  // epilogue: 32x32 C/D layout col=lane&31, row=(reg&3)+8*(reg>>2)+4*hi
  const int  ocol0 = (int)bcol + wn * 64;
  const long orow0 = brow + wm * 128;
  float soc[2], zpc[2], bc[2];
#pragma unroll
  for (int n = 0; n < 2; ++n) {
    int col = ocol0 + n * 32 + l31;
    soc[n] = dout[(long)e * N_ + col];
    zpc[n] = zp[col];
    bc[n]  = bias[col];
  }
#pragma unroll
  for (int m = 0; m < 4; ++m) {
    long mb = orow0 + m * 32 + 4 * hi;
#pragma unroll
    for (int r = 0; r < 16; ++r) {
      long row = mb + (r & 3) + 8 * (r >> 2);
      float sxr = sx[row], qfr = qf[row];
#pragma unroll
      for (int n = 0; n < 2; ++n) {
        int col = ocol0 + n * 32 + l31;
        float tv = (float)acc[m][n][r] - zpc[n] * qfr;
        C[row * N_ + col] = tv * (soc[n] * sxr) + bc[n];
      }
    }
  }
}

// ---------------- fallback (only if ws too small) ----------------
__global__ void naive_kernel(const float* __restrict__ x, const int* __restrict__ wi,
                             const float* __restrict__ zp, const float* __restrict__ dout,
                             const float* __restrict__ din, const float* __restrict__ bias,
                             const int* __restrict__ eidx, float* __restrict__ y) {
  long t = (long)blockIdx.x * blockDim.x + threadIdx.x;
  if (t >= (long)M_ * N_) return;
  int  o = (int)(t & (N_ - 1));
  long r = t >> 12;
  int  e = *eidx;
  float z  = zp[o];
  float so = dout[(long)e * N_ + o];
  const float* xr = x + r * K_;
  const int*   wrow = wi + (long)o * K_;
  const float* dr = din + (long)e * K_;
  float s = 0.f;
  for (int k = 0; k < K_; ++k)
    s += xr[k] * (((float)wrow[k] - z) * dr[k]);
  y[t] = s * so + bias[o];
}

extern "C" void kernel_launch(void* const* d_in, const int* in_sizes, int n_in,
                              void* d_out, int out_size, void* d_ws, size_t ws_size,
                              hipStream_t stream) {
  const float* x    = (const float*)d_in[0];
  const int*   wi   = (const int*)d_in[1];
  const float* zp   = (const float*)d_in[2];
  const float* dout = (const float*)d_in[3];
  const float* din  = (const float*)d_in[4];
  const float* bias = (const float*)d_in[5];
  const int*   eidx = (const int*)d_in[6];
  float* y = (float*)d_out;

  const size_t qB  = (size_t)M_ * K_;          // 33.5 MB
  const size_t wB  = (size_t)N_ * K_;          // 16.8 MB
  const size_t need = qB + wB + 2 * M_ * sizeof(float);
  if (ws_size >= need) {
    char*  q   = (char*)d_ws;
    char*  wq  = q + qB;
    float* sxp = (float*)(wq + wB);
    float* qfp = sxp + M_;
    quant_x<<<dim3(M_), dim3(256), 0, stream>>>(x, din, eidx, q, sxp, qfp);
    repack_w<<<dim3((unsigned)((size_t)N_ * K_ / 16 / 256)), dim3(256), 0, stream>>>(wi, wq);
    gemm_i8<<<dim3((M_ / 256) * (N_ / 256)), dim3(512), 65536, stream>>>(
        q, wq, zp, dout, bias, eidx, sxp, qfp, y);
  } else {
    long total = (long)M_ * N_;
    naive_kernel<<<dim3((unsigned)((total + 255) / 256)), dim3(256), 0, stream>>>(
        x, wi, zp, dout, din, bias, eidx, y);
  }
}

// Round 14
// 188.274 us; speedup vs baseline: 1.0371x; 1.0371x over previous
//
#include <hip/hip_runtime.h>
#include <cstdint>

#define M_ 8192
#define N_ 4096
#define K_ 4096

typedef int   i32x4 __attribute__((ext_vector_type(4)));

__device__ __forceinline__ void async16(const void* g, void* l) {
  __builtin_amdgcn_global_load_lds(
      (const __attribute__((address_space(1))) void*)g,
      (__attribute__((address_space(3))) void*)l, 16, 0, 0);
}

// ---------------- prologue 1: x*din -> per-row i8 quant + rowsum ----------------
__global__ __launch_bounds__(256) void quant_x(const float* __restrict__ x,
                                               const float* __restrict__ din,
                                               const int* __restrict__ eidx,
                                               char* __restrict__ q,
                                               float* __restrict__ sx,
                                               float* __restrict__ qf) {
  const int row = blockIdx.x;
  const int t = threadIdx.x;
  const int e = *eidx;
  const float* xr = x + (long)row * K_;
  const float* dr = din + (long)e * K_;
  const int k0 = t * 16;
  float v[16];
#pragma unroll
  for (int j = 0; j < 4; ++j) {
    float4 xv = *(const float4*)(xr + k0 + j * 4);
    float4 dv = *(const float4*)(dr + k0 + j * 4);
    v[j*4+0] = xv.x * dv.x; v[j*4+1] = xv.y * dv.y;
    v[j*4+2] = xv.z * dv.z; v[j*4+3] = xv.w * dv.w;
  }
  float mx = 0.f;
#pragma unroll
  for (int j = 0; j < 16; ++j) mx = fmaxf(mx, fabsf(v[j]));
#pragma unroll
  for (int off = 32; off >= 1; off >>= 1) mx = fmaxf(mx, __shfl_xor(mx, off));
  __shared__ float sm[4];
  __shared__ int   ss[4];
  const int wid = t >> 6, ln = t & 63;
  if (ln == 0) sm[wid] = mx;
  __syncthreads();
  mx = fmaxf(fmaxf(sm[0], sm[1]), fmaxf(sm[2], sm[3]));
  const float scale = (mx > 0.f) ? mx * (1.f / 127.f) : 1.f;
  const float rcp   = (mx > 0.f) ? 127.f / mx : 0.f;
  int ssum = 0;
  unsigned int dw[4];
#pragma unroll
  for (int c = 0; c < 4; ++c) {
    unsigned int w = 0;
#pragma unroll
    for (int j = 0; j < 4; ++j) {
      int qi = (int)rintf(v[c*4+j] * rcp);
      ssum += qi;
      w |= ((unsigned int)(qi & 255)) << (8 * j);
    }
    dw[c] = w;
  }
  *(int4*)(q + (long)row * K_ + k0) = make_int4((int)dw[0], (int)dw[1], (int)dw[2], (int)dw[3]);
#pragma unroll
  for (int off = 32; off >= 1; off >>= 1) ssum += __shfl_xor(ssum, off);
  if (ln == 0) ss[wid] = ssum;
  __syncthreads();
  if (t == 0) {
    sx[row] = scale;
    qf[row] = (float)(ss[0] + ss[1] + ss[2] + ss[3]);
  }
}

// ---------------- prologue 2: W_int (int32, 0..126) -> i8 ----------------
__global__ __launch_bounds__(256) void repack_w(const int* __restrict__ wi,
                                                char* __restrict__ wq) {
  const long t = (long)blockIdx.x * blockDim.x + threadIdx.x;   // 1,048,576
  const long base = t * 16;
  int4 a = *(const int4*)(wi + base);
  int4 b = *(const int4*)(wi + base + 4);
  int4 c = *(const int4*)(wi + base + 8);
  int4 d = *(const int4*)(wi + base + 12);
  unsigned int w0 = (a.x & 255) | ((a.y & 255) << 8) | ((a.z & 255) << 16) | ((unsigned)(a.w & 255) << 24);
  unsigned int w1 = (b.x & 255) | ((b.y & 255) << 8) | ((b.z & 255) << 16) | ((unsigned)(b.w & 255) << 24);
  unsigned int w2 = (c.x & 255) | ((c.y & 255) << 8) | ((c.z & 255) << 16) | ((unsigned)(c.w & 255) << 24);
  unsigned int w3 = (d.x & 255) | ((d.y & 255) << 8) | ((d.z & 255) << 16) | ((unsigned)(d.w & 255) << 24);
  *(int4*)(wq + base) = make_int4((int)w0, (int)w1, (int)w2, (int)w3);
}

// ---- main GEMM: i8, 256x256 tile, BK=64B, dbuf 2x32KB, 8 waves (2Mx4N) ----
// Round-12 structure (0 conflicts, proven) with ONE barrier per tile:
// per tile: VMC(0) [STAGE(t) landed; issued a full body ago -> ~free];
// BAR [buf t globally valid]; STAGE(t+1) [opposite buffer; all waves past
// BAR(t) -> their reads(t-1) of that buffer are consumed -> safe];
// 12 ds_read_b128 + 32 MFMA (compiler-scheduled, overlapping STAGE issue).
// Swizzle: slot ^= (row>>1)&3 (both sides, rule #21) -> 0 bank conflicts.
#define VMC(n)   asm volatile("s_waitcnt vmcnt(" #n ")" ::: "memory")
#define BAR()    __builtin_amdgcn_s_barrier()

__global__ __launch_bounds__(512, 2) void gemm_i8(const char* __restrict__ A8,
                                                  const char* __restrict__ B8,
                                                  const float* __restrict__ zp,
                                                  const float* __restrict__ dout,
                                                  const float* __restrict__ bias,
                                                  const int* __restrict__ eidx,
                                                  const float* __restrict__ sx,
                                                  const float* __restrict__ qf,
                                                  float* __restrict__ C) {
  extern __shared__ char ldsb[];
  const int tid  = threadIdx.x;
  const int lane = tid & 63;
  const int wave = tid >> 6;
  const int wm = wave >> 2;            // 0..1 -> 128-row half
  const int wn = wave & 3;             // 0..3 -> 64-col quarter
  const int fr = lane & 15, fq = lane >> 4;
  const int e = *eidx;

  // XCD-aware swizzle (512 % 8 == 0 -> bijective)
  const int nwg = gridDim.x;
  const int wg  = blockIdx.x;
  const int swz = (wg & 7) * (nwg >> 3) + (wg >> 3);
  const int bm = swz >> 4;
  const int bn = swz & 15;
  const long brow = (long)bm * 256;
  const long bcol = (long)bn * 256;

  // staging: thread t -> row tid>>2 (0..127), LDS slot tid&3 (linear dest);
  // global source slot = (tid&3) ^ ((row>>1)&3); (row+128) keeps same XOR.
  const int gslot = (tid & 3) ^ ((tid >> 3) & 3);
  const char* pa = A8 + (brow + (tid >> 2)) * (long)K_ + gslot * 16;
  const char* pb = B8 + (bcol + (tid >> 2)) * (long)K_ + gslot * 16;

  auto STAGE = [&](int tile) {
    char* d = ldsb + (tile & 1) * 32768 + tid * 16;
    const long ko = (long)tile * 64;
    async16(pa + ko,                  d);
    async16(pa + ko + 128 * (long)K_, d + 8192);
    async16(pb + ko,                  d + 16384);
    async16(pb + ko + 128 * (long)K_, d + 24576);
  };

  // ds_read byte offsets; swizzled slot = fq ^ ((fr>>1)&3) (constant per lane)
  const int rslot = (fq ^ ((fr >> 1) & 3)) * 16;
  int rA[8], rB[4];
#pragma unroll
  for (int m = 0; m < 8; ++m) rA[m] = (wm * 128 + m * 16 + fr) * 64 + rslot;
#pragma unroll
  for (int n = 0; n < 4; ++n) rB[n] = 16384 + (wn * 64 + n * 16 + fr) * 64 + rslot;

  i32x4 acc[8][4] = {};
  const int nk = K_ / 64;              // 64 K-tiles (64 bytes each)

  STAGE(0);
  for (int t = 0; t < nk; ++t) {
    VMC(0);                            // own STAGE(t) landed (issued 1 body ago)
    BAR();                             // all waves' STAGE(t) landed -> buf t valid
    if (t + 1 < nk) STAGE(t + 1);      // opposite buffer; overlaps compute
    const char* bp = ldsb + (t & 1) * 32768;
    i32x4 av[8], bv[4];
#pragma unroll
    for (int n = 0; n < 4; ++n) bv[n] = *(const i32x4*)(bp + rB[n]);
#pragma unroll
    for (int m = 0; m < 8; ++m) av[m] = *(const i32x4*)(bp + rA[m]);
#pragma unroll
    for (int m = 0; m < 8; ++m)
#pragma unroll
      for (int n = 0; n < 4; ++n)
        acc[m][n] = __builtin_amdgcn_mfma_i32_16x16x64_i8(av[m], bv[n], acc[m][n], 0, 0, 0);
  }

  // epilogue: C/D layout col=lane&15, row=(lane>>4)*4+reg [m89; dtype-indep]
  const int  ocol0 = (int)bcol + wn * 64;
  const long orow0 = brow + wm * 128;
  float soc[4], zpc[4], bc[4];
#pragma unroll
  for (int n = 0; n < 4; ++n) {
    int col = ocol0 + n * 16 + fr;
    soc[n] = dout[(long)e * N_ + col];
    zpc[n] = zp[col];
    bc[n]  = bias[col];
  }
#pragma unroll
  for (int m = 0; m < 8; ++m) {
    long rb = orow0 + m * 16 + fq * 4;
    float sxr[4], qfr[4];
#pragma unroll
    for (int j = 0; j < 4; ++j) { sxr[j] = sx[rb + j]; qfr[j] = qf[rb + j]; }
#pragma unroll
    for (int n = 0; n < 4; ++n) {
      int col = ocol0 + n * 16 + fr;
#pragma unroll
      for (int j = 0; j < 4; ++j) {
        float tv = (float)acc[m][n][j] - zpc[n] * qfr[j];
        C[(rb + j) * N_ + col] = tv * (soc[n] * sxr[j]) + bc[n];
      }
    }
  }
}

// ---------------- fallback (only if ws too small) ----------------
__global__ void naive_kernel(const float* __restrict__ x, const int* __restrict__ wi,
                             const float* __restrict__ zp, const float* __restrict__ dout,
                             const float* __restrict__ din, const float* __restrict__ bias,
                             const int* __restrict__ eidx, float* __restrict__ y) {
  long t = (long)blockIdx.x * blockDim.x + threadIdx.x;
  if (t >= (long)M_ * N_) return;
  int  o = (int)(t & (N_ - 1));
  long r = t >> 12;
  int  e = *eidx;
  float z  = zp[o];
  float so = dout[(long)e * N_ + o];
  const float* xr = x + r * K_;
  const int*   wrow = wi + (long)o * K_;
  const float* dr = din + (long)e * K_;
  float s = 0.f;
  for (int k = 0; k < K_; ++k)
    s += xr[k] * (((float)wrow[k] - z) * dr[k]);
  y[t] = s * so + bias[o];
}

extern "C" void kernel_launch(void* const* d_in, const int* in_sizes, int n_in,
                              void* d_out, int out_size, void* d_ws, size_t ws_size,
                              hipStream_t stream) {
  const float* x    = (const float*)d_in[0];
  const int*   wi   = (const int*)d_in[1];
  const float* zp   = (const float*)d_in[2];
  const float* dout = (const float*)d_in[3];
  const float* din  = (const float*)d_in[4];
  const float* bias = (const float*)d_in[5];
  const int*   eidx = (const int*)d_in[6];
  float* y = (float*)d_out;

  const size_t qB  = (size_t)M_ * K_;          // 33.5 MB
  const size_t wB  = (size_t)N_ * K_;          // 16.8 MB
  const size_t need = qB + wB + 2 * M_ * sizeof(float);
  if (ws_size >= need) {
    char*  q   = (char*)d_ws;
    char*  wq  = q + qB;
    float* sxp = (float*)(wq + wB);
    float* qfp = sxp + M_;
    quant_x<<<dim3(M_), dim3(256), 0, stream>>>(x, din, eidx, q, sxp, qfp);
    repack_w<<<dim3((unsigned)((size_t)N_ * K_ / 16 / 256)), dim3(256), 0, stream>>>(wi, wq);
    gemm_i8<<<dim3((M_ / 256) * (N_ / 256)), dim3(512), 65536, stream>>>(
        q, wq, zp, dout, bias, eidx, sxp, qfp, y);
  } else {
    long total = (long)M_ * N_;
    naive_kernel<<<dim3((unsigned)((total + 255) / 256)), dim3(256), 0, stream>>>(
        x, wi, zp, dout, din, bias, eidx, y);
  }
}